// Round 16
// baseline (132.422 us; speedup 1.0000x reference)
//
#include <hip/hip_runtime.h>
#include <stdint.h>

#define B_ 2
#define C_ 256
#define H_ 96
#define W_ 96
#define HW_ (H_*W_)

typedef _Float16 half8 __attribute__((ext_vector_type(8)));
typedef float f32x4 __attribute__((ext_vector_type(4)));

// ---- workspace byte layout ----
#define ZPOFF   0u          // 512 B zero page
#define CNTOFF  512u        // int cnt[576]
#define PERMOFF 4096u       // int perm[576][96]
#define F1OFF   225280u     // f16 (B,HW,C) f1, pre-scaled 1/16
#define L0OFF   9662464u
#define L1OFF   19099648u
#define L2OFF   21458944u
#define L3OFF   22048768u
#define SCROFF  22196224u   // f16 scr[B*HW][328]  (4 levels x 82, dword-aligned)
// end: 22196224 + 18432*656 = 34287616

#define CAP 96
#define DLW 226

// ---------- fused transpose: f1 -> f1t (scaled), f2 -> L0 ----------
__global__ __launch_bounds__(256) void k_tr2(const float* __restrict__ f1,
                                             const float* __restrict__ f2,
                                             _Float16* __restrict__ f1t,
                                             _Float16* __restrict__ L0h) {
  __shared__ float t[32][33];
  const int z = blockIdx.z;
  const int b = z & 1;
  const bool is2 = (z >> 1) != 0;
  const float* in = is2 ? f2 : f1;
  _Float16* out = is2 ? L0h : f1t;
  const float scale = is2 ? 1.0f : 0.0625f;

  const int p0 = blockIdx.x * 32, c0 = blockIdx.y * 32;
  const int tx = threadIdx.x, ty = threadIdx.y;
  const float* src = in + ((size_t)b * C_ + c0) * HW_ + p0;
#pragma unroll
  for (int i = 0; i < 4; ++i)
    t[ty + 8 * i][tx] = src[(size_t)(ty + 8 * i) * HW_ + tx];
  __syncthreads();
  _Float16* dst = out + ((size_t)b * HW_ + p0) * C_ + c0;
#pragma unroll
  for (int i = 0; i < 4; ++i)
    dst[(size_t)(ty + 8 * i) * C_ + tx] = (_Float16)(t[tx][ty + 8 * i] * scale);
}

// ---------- fused pools: L1, L2, L3 straight from L0 ----------
__global__ __launch_bounds__(256) void k_pool3(const _Float16* __restrict__ L0,
                                               _Float16* __restrict__ L1,
                                               _Float16* __restrict__ L2,
                                               _Float16* __restrict__ L3) {
  int idx = blockIdx.x;
  const int X = idx % 12; idx /= 12;
  const int Y = idx % 12; const int b = idx / 12;
  const int c = threadIdx.x;

  const _Float16* base = L0 + (((size_t)b * 96 + 8 * Y) * 96 + 8 * X) * C_ + c;
  float s1[4][4];
#pragma unroll
  for (int i = 0; i < 4; ++i)
#pragma unroll
    for (int j = 0; j < 4; ++j) {
      const _Float16* p = base + ((size_t)(2 * i) * 96 + 2 * j) * C_;
      s1[i][j] = ((float)p[0] + (float)p[C_] +
                  (float)p[96 * C_] + (float)p[96 * C_ + C_]) * 0.25f;
    }
#pragma unroll
  for (int i = 0; i < 4; ++i)
#pragma unroll
    for (int j = 0; j < 4; ++j)
      L1[(((size_t)b * 48 + 4 * Y + i) * 48 + 4 * X + j) * C_ + c] = (_Float16)s1[i][j];

  float s2[2][2];
#pragma unroll
  for (int i = 0; i < 2; ++i)
#pragma unroll
    for (int j = 0; j < 2; ++j) {
      s2[i][j] = (s1[2 * i][2 * j] + s1[2 * i][2 * j + 1] +
                  s1[2 * i + 1][2 * j] + s1[2 * i + 1][2 * j + 1]) * 0.25f;
      L2[(((size_t)b * 24 + 2 * Y + i) * 24 + 2 * X + j) * C_ + c] = (_Float16)s2[i][j];
    }

  const float s3 = (s2[0][0] + s2[0][1] + s2[1][0] + s2[1][1]) * 0.25f;
  L3[(((size_t)b * 12 + Y) * 12 + X) * C_ + c] = (_Float16)s3;
}

// ---------- bucket into 8x4-px supercells ----------
__global__ __launch_bounds__(256) void k_bucket(const float* __restrict__ cent,
                                                int* __restrict__ cnt,
                                                int* __restrict__ perm) {
  const int t = blockIdx.x * 256 + threadIdx.x;
  const int b = t / HW_, yx = t - b * HW_;
  const float cx = cent[(size_t)b * 2 * HW_ + yx];
  const float cy = cent[(size_t)b * 2 * HW_ + HW_ + yx];
  int ci = (int)(cx * 0.125f); ci = min(max(ci, 0), 11);
  int cj = (int)(cy * 0.25f);  cj = min(max(cj, 0), 23);
  const int cell = b * 288 + cj * 12 + ci;
  const int pos = atomicAdd(&cnt[cell], 1);
  if (pos < CAP) perm[cell * CAP + pos] = t;
}

// ---------- per-(supercell,level) single-wave GEMM + packed epilogue ----------
// mode bit0: real B-gather (else zero-page uniform loads)
// mode bit1: run epilogue store loop
template <int LVL>
__device__ __forceinline__ void cell_level(char* __restrict__ ws,
                                           const float* __restrict__ cent,
                                           int b, int ci, int cj,
                                           const int* __restrict__ pc, int npix,
                                           _Float16* __restrict__ dl,
                                           float* __restrict__ prm, int lane,
                                           int mode) {
  constexpr int wl = 96 >> LVL;
  constexpr int Wx = (LVL == 0) ? 17 : (LVL == 1) ? 13 : (LVL == 2) ? 11 : 10;
  constexpr int Hy = (LVL == 0) ? 13 : (LVL == 1) ? 11 : 10;
  constexpr int N = Wx * Hy;
  constexpr int ntiles = (N + 15) >> 4;
  constexpr uint32_t LB = (LVL == 0) ? L0OFF : (LVL == 1) ? L1OFF
                        : (LVL == 2) ? L2OFF : L3OFF;
  constexpr uint32_t PBl = (LVL == 0) ? 4718592u : (LVL == 1) ? 1179648u
                         : (LVL == 2) ? 294912u : 73728u;
  constexpr float inv = 1.0f / (float)(1 << LVL);

  const int FXl = (LVL == 0) ? (ci << 3) : (LVL == 1) ? (ci << 2)
                : (LVL == 2) ? (ci << 1) : ci;
  const int FYl = (LVL == 0) ? (cj << 2) : (LVL == 1) ? (cj << 1)
                : (LVL == 2) ? cj : (cj >> 1);
  const int XW0 = FXl - 4, YW0 = FYl - 4;
  const char* lbase = ws + LB + (size_t)b * PBl;
  const char* zp = ws + ZPOFF;
  const char* f1b = ws + F1OFF;
  char* scrb = ws + SCROFF;

  const int row16 = lane & 15, kb = lane >> 4;
  const int nmt = (npix + 47) / 48;
  const bool realB = (mode & 1) != 0;
  const bool doSt  = (mode & 2) != 0;

  for (int mt = 0; mt < nmt; ++mt) {
    const int rem = npix - mt * 48;            // wave-uniform
    const int remc = min(rem, 48);

    half8 av0[8], av1[8], av2[8];
    {
      const int i0 = mt * 48 + row16;
      const int pv0 = (i0 < npix) ? pc[i0] : pc[0];
      const char* a0 = f1b + (size_t)pv0 * 512 + kb * 16;
#pragma unroll
      for (int k = 0; k < 8; ++k) av0[k] = *(const half8*)(a0 + k * 64);
    }
    if (rem > 16) {
      const int i1 = mt * 48 + 16 + row16;
      const int pv1 = (i1 < npix) ? pc[i1] : pc[0];
      const char* a1 = f1b + (size_t)pv1 * 512 + kb * 16;
#pragma unroll
      for (int k = 0; k < 8; ++k) av1[k] = *(const half8*)(a1 + k * 64);
    }
    if (rem > 32) {
      const int i2 = mt * 48 + 32 + row16;
      const int pv2 = (i2 < npix) ? pc[i2] : pc[0];
      const char* a2 = f1b + (size_t)pv2 * 512 + kb * 16;
#pragma unroll
      for (int k = 0; k < 8; ++k) av2[k] = *(const half8*)(a2 + k * 64);
    }

    if (lane < remc) {
      const int pv = pc[mt * 48 + lane];
      const int yx = pv - b * HW_;
      const float cx = cent[(size_t)b * 2 * HW_ + yx];
      const float cy = cent[(size_t)b * 2 * HW_ + HW_ + yx];
      const float cxl = cx * inv, cyl = cy * inv;
      const float fxl = floorf(cxl), fyl = floorf(cyl);
      const int sxp = (int)fxl - FXl, syp = (int)fyl - FYl;
      prm[lane * 4 + 0] = cxl - fxl;
      prm[lane * 4 + 1] = cyl - fyl;
      ((int*)prm)[lane * 4 + 2] = syp * Wx + sxp;
      ((int*)prm)[lane * 4 + 3] = pv;
    }

#pragma unroll
    for (int j = 0; j < ntiles; ++j) {
      const int n = j * 16 + row16;
      const int sy = n / Wx, sx = n - sy * Wx;
      const int gy = YW0 + sy, gx = XW0 + sx;
      const bool val = realB & (n < N) & (gy >= 0) & (gy < wl) & (gx >= 0) & (gx < wl);
      const char* bp = (val ? (lbase + (((size_t)(gy * wl + gx)) << 9)) : zp)
                       + kb * 16;
      half8 bv[8];
#pragma unroll
      for (int k = 0; k < 8; ++k) bv[k] = *(const half8*)(bp + k * 64);

      f32x4 acc0 = {0.f, 0.f, 0.f, 0.f};
#pragma unroll
      for (int k = 0; k < 8; ++k)
        acc0 = __builtin_amdgcn_mfma_f32_16x16x32_f16(av0[k], bv[k], acc0, 0, 0, 0);
      const int col = j * 16 + row16;
#pragma unroll
      for (int j4 = 0; j4 < 4; ++j4)
        dl[(kb * 4 + j4) * DLW + col] = (_Float16)acc0[j4];

      if (rem > 16) {
        f32x4 acc1 = {0.f, 0.f, 0.f, 0.f};
#pragma unroll
        for (int k = 0; k < 8; ++k)
          acc1 = __builtin_amdgcn_mfma_f32_16x16x32_f16(av1[k], bv[k], acc1, 0, 0, 0);
#pragma unroll
        for (int j4 = 0; j4 < 4; ++j4)
          dl[(kb * 4 + j4 + 16) * DLW + col] = (_Float16)acc1[j4];
      }
      if (rem > 32) {
        f32x4 acc2 = {0.f, 0.f, 0.f, 0.f};
#pragma unroll
        for (int k = 0; k < 8; ++k)
          acc2 = __builtin_amdgcn_mfma_f32_16x16x32_f16(av2[k], bv[k], acc2, 0, 0, 0);
#pragma unroll
        for (int j4 = 0; j4 < 4; ++j4)
          dl[(kb * 4 + j4 + 32) * DLW + col] = (_Float16)acc2[j4];
      }
    }

    if (doSt) {
      const int total = remc * 41;
      for (int s = lane; s < total; s += 64) {
        const int p = s / 41;
        const int c = s - p * 41;
        const float wx1 = prm[p * 4 + 0];
        const float wy1 = prm[p * 4 + 1];
        const int n0 = ((const int*)prm)[p * 4 + 2];
        const int pv = ((const int*)prm)[p * 4 + 3];
        const float wx0 = 1.f - wx1, wy0 = 1.f - wy1;
        const _Float16* d = &dl[p * DLW];
        uint32_t packed = 0;
#pragma unroll
        for (int e = 0; e < 2; ++e) {
          const int o = 2 * c + e;
          const int a = o / 9, bq = o - a * 9;
          const int n = n0 + bq * Wx + a;
          const float d00 = (float)d[n],      d10 = (float)d[n + 1];
          const float d01 = (float)d[n + Wx], d11 = (float)d[n + Wx + 1];
          const float v = wy0 * (wx0 * d00 + wx1 * d10) +
                          wy1 * (wx0 * d01 + wx1 * d11);
          const _Float16 h = (_Float16)v;
          packed |= ((uint32_t)*(const uint16_t*)&h) << (16 * e);
        }
        *(uint32_t*)(scrb + (size_t)pv * 656 + LVL * 164 + c * 4) = packed;
      }
    }
  }
}

__global__ __launch_bounds__(64, 2) void k_cell(char* __restrict__ ws,
                                                const float* __restrict__ cent,
                                                int mode) {
  __shared__ _Float16 dl[48 * DLW];   // 21.2 KB
  __shared__ float prm[48 * 4];

  const int bx = blockIdx.x;                 // 0..2303
  const int xcd = bx & 7, slot = bx >> 3;    // slot 0..287
  const int b = xcd >> 2, band = xcd & 3;
  const int lvl = slot / 72;
  const int rem = slot - lvl * 72;
  const int cjb = rem / 12, ci = rem - cjb * 12;
  const int cj = band * 6 + cjb;
  const int cell = b * 288 + cj * 12 + ci;

  const int* cnt = (const int*)(ws + CNTOFF);
  const int npix = min(cnt[cell], CAP);
  if (npix == 0) return;
  const int* pc = (const int*)(ws + PERMOFF) + cell * CAP;

  const int lane = threadIdx.x;
  switch (lvl) {
    case 0: cell_level<0>(ws, cent, b, ci, cj, pc, npix, dl, prm, lane, mode); break;
    case 1: cell_level<1>(ws, cent, b, ci, cj, pc, npix, dl, prm, lane, mode); break;
    case 2: cell_level<2>(ws, cent, b, ci, cj, pc, npix, dl, prm, lane, mode); break;
    default: cell_level<3>(ws, cent, b, ci, cj, pc, npix, dl, prm, lane, mode); break;
  }
}

// ---------- final transpose: scr[B*HW][328] f16 -> out[B][324][HW] f32 ----------
__global__ __launch_bounds__(256) void k_otrans(const _Float16* __restrict__ scr,
                                                float* __restrict__ out) {
  __shared__ float t[32][33];
  const int b = blockIdx.z;
  const int yx0 = blockIdx.x * 32, c0 = blockIdx.y * 32;
  const int tx = threadIdx.x, ty = threadIdx.y;
#pragma unroll
  for (int i = 0; i < 4; ++i) {
    const int yxi = ty + 8 * i, c = c0 + tx;
    float v = 0.f;
    if (c < 324) {
      const int lv = c / 81, o = c - lv * 81;
      v = (float)scr[((size_t)b * HW_ + yx0 + yxi) * 328 + lv * 82 + o];
    }
    t[yxi][tx] = v;
  }
  __syncthreads();
#pragma unroll
  for (int i = 0; i < 4; ++i) {
    const int c = c0 + ty + 8 * i;
    if (c < 324)
      out[((size_t)b * 324 + c) * HW_ + yx0 + tx] = t[tx][ty + 8 * i];
  }
}

extern "C" void kernel_launch(void* const* d_in, const int* in_sizes, int n_in,
                              void* d_out, int out_size, void* d_ws, size_t ws_size,
                              hipStream_t stream) {
  (void)in_sizes; (void)n_in; (void)out_size; (void)ws_size;
  const float* f1   = (const float*)d_in[0];
  const float* f2   = (const float*)d_in[1];
  const float* cent = (const float*)d_in[2];
  float* out = (float*)d_out;

  char* ws = (char*)d_ws;
  _Float16* f1t = (_Float16*)(ws + F1OFF);
  _Float16* L0  = (_Float16*)(ws + L0OFF);
  _Float16* L1  = (_Float16*)(ws + L1OFF);
  _Float16* L2  = (_Float16*)(ws + L2OFF);
  _Float16* L3  = (_Float16*)(ws + L3OFF);
  int* cnt  = (int*)(ws + CNTOFF);
  int* perm = (int*)(ws + PERMOFF);

  (void)hipMemsetAsync(ws, 0, 4096, stream);   // zero page + cnt

  hipLaunchKernelGGL(k_bucket, dim3(72), dim3(256), 0, stream, cent, cnt, perm);

  dim3 tb(32, 8, 1);
  hipLaunchKernelGGL(k_tr2, dim3(HW_ / 32, C_ / 32, 2 * B_), tb, 0, stream,
                     f1, f2, f1t, L0);
  hipLaunchKernelGGL(k_pool3, dim3(B_ * 12 * 12), dim3(256), 0, stream,
                     L0, L1, L2, L3);

  // ABLATION: mode=0 (no scatter, no stores) -> GEMM/LDS floor
  //           mode=1 (real gather, no stores) -> +gather cost
  //           mode=3 (full, runs LAST -> correct scr)
  hipLaunchKernelGGL(k_cell, dim3(2304), dim3(64), 0, stream, ws, cent, 0);
  hipLaunchKernelGGL(k_cell, dim3(2304), dim3(64), 0, stream, ws, cent, 1);
  hipLaunchKernelGGL(k_cell, dim3(2304), dim3(64), 0, stream, ws, cent, 3);

  hipLaunchKernelGGL(k_otrans, dim3(HW_ / 32, 11, B_), tb, 0, stream,
                     (const _Float16*)(ws + SCROFF), out);
}

// Round 17
// 89.140 us; speedup vs baseline: 1.4856x; 1.4856x over previous
//
#include <hip/hip_runtime.h>
#include <stdint.h>

#define B_ 2
#define C_ 256
#define H_ 96
#define W_ 96
#define HW_ (H_*W_)

typedef _Float16 half8 __attribute__((ext_vector_type(8)));
typedef float f32x4 __attribute__((ext_vector_type(4)));

// ---- workspace byte layout ----
#define ZPOFF   0u          // 512 B zero page
#define CNTOFF  512u        // int cnt[576]
#define PERMOFF 4096u       // int perm[576][96]
#define F1OFF   225280u     // f16 (B,HW,C) f1, pre-scaled 1/16
#define L0OFF   9662464u
#define L1OFF   19099648u
#define L2OFF   21458944u
#define L3OFF   22048768u
#define SCROFF  22196224u   // f16 scr[B*HW][328]  (4 levels x 82, dword-aligned)
// end: 34287616

#define CAP 96
#define DLW 226

// ---------- fused transpose: f1 -> f1t (scaled), f2 -> L0 ----------
__global__ __launch_bounds__(256) void k_tr2(const float* __restrict__ f1,
                                             const float* __restrict__ f2,
                                             _Float16* __restrict__ f1t,
                                             _Float16* __restrict__ L0h) {
  __shared__ float t[32][33];
  const int z = blockIdx.z;
  const int b = z & 1;
  const bool is2 = (z >> 1) != 0;
  const float* in = is2 ? f2 : f1;
  _Float16* out = is2 ? L0h : f1t;
  const float scale = is2 ? 1.0f : 0.0625f;

  const int p0 = blockIdx.x * 32, c0 = blockIdx.y * 32;
  const int tx = threadIdx.x, ty = threadIdx.y;
  const float* src = in + ((size_t)b * C_ + c0) * HW_ + p0;
#pragma unroll
  for (int i = 0; i < 4; ++i)
    t[ty + 8 * i][tx] = src[(size_t)(ty + 8 * i) * HW_ + tx];
  __syncthreads();
  _Float16* dst = out + ((size_t)b * HW_ + p0) * C_ + c0;
#pragma unroll
  for (int i = 0; i < 4; ++i)
    dst[(size_t)(ty + 8 * i) * C_ + tx] = (_Float16)(t[tx][ty + 8 * i] * scale);
}

// ---------- fused pools (L1,L2,L3 from L0) + bucket prepass ----------
__global__ __launch_bounds__(256) void k_pool3(const _Float16* __restrict__ L0,
                                               _Float16* __restrict__ L1,
                                               _Float16* __restrict__ L2,
                                               _Float16* __restrict__ L3,
                                               const float* __restrict__ cent,
                                               int* __restrict__ cnt,
                                               int* __restrict__ perm) {
  // fused bucket: first 36864 threads classify one pixel each
  {
    const int t = blockIdx.x * 256 + threadIdx.x;
    if (t < B_ * HW_) {
      const int b = t / HW_, yx = t - b * HW_;
      const float cx = cent[(size_t)b * 2 * HW_ + yx];
      const float cy = cent[(size_t)b * 2 * HW_ + HW_ + yx];
      int ci = (int)(cx * 0.125f); ci = min(max(ci, 0), 11);
      int cj = (int)(cy * 0.25f);  cj = min(max(cj, 0), 23);
      const int cell = b * 288 + cj * 12 + ci;
      const int pos = atomicAdd(&cnt[cell], 1);
      if (pos < CAP) perm[cell * CAP + pos] = t;
    }
  }

  int idx = blockIdx.x;
  const int X = idx % 12; idx /= 12;
  const int Y = idx % 12; const int b = idx / 12;
  const int c = threadIdx.x;

  const _Float16* base = L0 + (((size_t)b * 96 + 8 * Y) * 96 + 8 * X) * C_ + c;
  float s1[4][4];
#pragma unroll
  for (int i = 0; i < 4; ++i)
#pragma unroll
    for (int j = 0; j < 4; ++j) {
      const _Float16* p = base + ((size_t)(2 * i) * 96 + 2 * j) * C_;
      s1[i][j] = ((float)p[0] + (float)p[C_] +
                  (float)p[96 * C_] + (float)p[96 * C_ + C_]) * 0.25f;
    }
#pragma unroll
  for (int i = 0; i < 4; ++i)
#pragma unroll
    for (int j = 0; j < 4; ++j)
      L1[(((size_t)b * 48 + 4 * Y + i) * 48 + 4 * X + j) * C_ + c] = (_Float16)s1[i][j];

  float s2[2][2];
#pragma unroll
  for (int i = 0; i < 2; ++i)
#pragma unroll
    for (int j = 0; j < 2; ++j) {
      s2[i][j] = (s1[2 * i][2 * j] + s1[2 * i][2 * j + 1] +
                  s1[2 * i + 1][2 * j] + s1[2 * i + 1][2 * j + 1]) * 0.25f;
      L2[(((size_t)b * 24 + 2 * Y + i) * 24 + 2 * X + j) * C_ + c] = (_Float16)s2[i][j];
    }

  const float s3 = (s2[0][0] + s2[0][1] + s2[1][0] + s2[1][1]) * 0.25f;
  L3[(((size_t)b * 12 + Y) * 12 + X) * C_ + c] = (_Float16)s3;
}

// ---------- one level of a pair-task (A-fragments passed in) ----------
template <int LVL>
__device__ __forceinline__ void do_level(char* __restrict__ ws,
                                         const float* __restrict__ cent,
                                         int b, int ci, int cj,
                                         const int* __restrict__ pc, int npix,
                                         int mt, int rem,
                                         const half8 (&av0)[8],
                                         const half8 (&av1)[8],
                                         const half8 (&av2)[8],
                                         _Float16* __restrict__ dl,
                                         float* __restrict__ prm, int lane) {
  constexpr int wl = 96 >> LVL;
  constexpr int Wx = (LVL == 0) ? 17 : (LVL == 1) ? 13 : (LVL == 2) ? 11 : 10;
  constexpr int Hy = (LVL == 0) ? 13 : (LVL == 1) ? 11 : 10;
  constexpr int N = Wx * Hy;
  constexpr int ntiles = (N + 15) >> 4;
  constexpr uint32_t LB = (LVL == 0) ? L0OFF : (LVL == 1) ? L1OFF
                        : (LVL == 2) ? L2OFF : L3OFF;
  constexpr uint32_t PBl = (LVL == 0) ? 4718592u : (LVL == 1) ? 1179648u
                         : (LVL == 2) ? 294912u : 73728u;
  constexpr float inv = 1.0f / (float)(1 << LVL);

  const int FXl = (LVL == 0) ? (ci << 3) : (LVL == 1) ? (ci << 2)
                : (LVL == 2) ? (ci << 1) : ci;
  const int FYl = (LVL == 0) ? (cj << 2) : (LVL == 1) ? (cj << 1)
                : (LVL == 2) ? cj : (cj >> 1);
  const int XW0 = FXl - 4, YW0 = FYl - 4;
  const char* lbase = ws + LB + (size_t)b * PBl;
  const char* zp = ws + ZPOFF;
  char* scrb = ws + SCROFF;

  const int row16 = lane & 15, kb = lane >> 4;
  const int remc = min(rem, 48);

  // per-pixel bilinear params (one lane per pixel)
  if (lane < remc) {
    const int pv = pc[mt * 48 + lane];
    const int yx = pv - b * HW_;
    const float cx = cent[(size_t)b * 2 * HW_ + yx];
    const float cy = cent[(size_t)b * 2 * HW_ + HW_ + yx];
    const float cxl = cx * inv, cyl = cy * inv;
    const float fxl = floorf(cxl), fyl = floorf(cyl);
    const int sxp = (int)fxl - FXl, syp = (int)fyl - FYl;
    prm[lane * 4 + 0] = cxl - fxl;
    prm[lane * 4 + 1] = cyl - fyl;
    ((int*)prm)[lane * 4 + 2] = syp * Wx + sxp;
    ((int*)prm)[lane * 4 + 3] = pv;
  }

#pragma unroll
  for (int j = 0; j < ntiles; ++j) {
    const int n = j * 16 + row16;
    const int sy = n / Wx, sx = n - sy * Wx;
    const int gy = YW0 + sy, gx = XW0 + sx;
    const bool val = (n < N) & (gy >= 0) & (gy < wl) & (gx >= 0) & (gx < wl);
    const char* bp = (val ? (lbase + (((size_t)(gy * wl + gx)) << 9)) : zp)
                     + kb * 16;
    half8 bv[8];
#pragma unroll
    for (int k = 0; k < 8; ++k) bv[k] = *(const half8*)(bp + k * 64);

    f32x4 acc0 = {0.f, 0.f, 0.f, 0.f};
#pragma unroll
    for (int k = 0; k < 8; ++k)
      acc0 = __builtin_amdgcn_mfma_f32_16x16x32_f16(av0[k], bv[k], acc0, 0, 0, 0);
    const int col = j * 16 + row16;
#pragma unroll
    for (int j4 = 0; j4 < 4; ++j4)
      dl[(kb * 4 + j4) * DLW + col] = (_Float16)acc0[j4];

    if (rem > 16) {
      f32x4 acc1 = {0.f, 0.f, 0.f, 0.f};
#pragma unroll
      for (int k = 0; k < 8; ++k)
        acc1 = __builtin_amdgcn_mfma_f32_16x16x32_f16(av1[k], bv[k], acc1, 0, 0, 0);
#pragma unroll
      for (int j4 = 0; j4 < 4; ++j4)
        dl[(kb * 4 + j4 + 16) * DLW + col] = (_Float16)acc1[j4];
    }
    if (rem > 32) {
      f32x4 acc2 = {0.f, 0.f, 0.f, 0.f};
#pragma unroll
      for (int k = 0; k < 8; ++k)
        acc2 = __builtin_amdgcn_mfma_f32_16x16x32_f16(av2[k], bv[k], acc2, 0, 0, 0);
#pragma unroll
      for (int j4 = 0; j4 < 4; ++j4)
        dl[(kb * 4 + j4 + 32) * DLW + col] = (_Float16)acc2[j4];
    }
  }

  // packed epilogue: 2 outputs per lane, one 4-B store
  {
    const int total = remc * 41;
    for (int s = lane; s < total; s += 64) {
      const int p = s / 41;
      const int c = s - p * 41;
      const float wx1 = prm[p * 4 + 0];
      const float wy1 = prm[p * 4 + 1];
      const int n0 = ((const int*)prm)[p * 4 + 2];
      const int pv = ((const int*)prm)[p * 4 + 3];
      const float wx0 = 1.f - wx1, wy0 = 1.f - wy1;
      const _Float16* d = &dl[p * DLW];
      uint32_t packed = 0;
#pragma unroll
      for (int e = 0; e < 2; ++e) {
        const int o = 2 * c + e;
        const int a = o / 9, bq = o - a * 9;
        const int n = n0 + bq * Wx + a;
        const float d00 = (float)d[n],      d10 = (float)d[n + 1];
        const float d01 = (float)d[n + Wx], d11 = (float)d[n + Wx + 1];
        const float v = wy0 * (wx0 * d00 + wx1 * d10) +
                        wy1 * (wx0 * d01 + wx1 * d11);
        const _Float16 h = (_Float16)v;
        packed |= ((uint32_t)*(const uint16_t*)&h) << (16 * e);
      }
      *(uint32_t*)(scrb + (size_t)pv * 656 + LVL * 164 + c * 4) = packed;
    }
  }
}

// pair-task kernel: task = (supercell, level-pair); A loaded once per pair
__global__ __launch_bounds__(64, 2) void k_cell(char* __restrict__ ws,
                                                const float* __restrict__ cent) {
  __shared__ _Float16 dl[48 * DLW];   // 21.2 KB
  __shared__ float prm[48 * 4];

  const int bx = blockIdx.x;                 // 0..1151
  const int xcd = bx & 7, slot = bx >> 3;    // slot 0..143
  const int b = xcd >> 2, band = xcd & 3;
  const int pair = slot / 72;                // 0: {L0,L3}  1: {L1,L2}
  const int rem2 = slot - pair * 72;
  const int cjb = rem2 / 12, ci = rem2 - cjb * 12;
  const int cj = band * 6 + cjb;
  const int cell = b * 288 + cj * 12 + ci;

  const int* cnt = (const int*)(ws + CNTOFF);
  const int npix = min(cnt[cell], CAP);
  if (npix == 0) return;
  const int* pc = (const int*)(ws + PERMOFF) + cell * CAP;

  const int lane = threadIdx.x;
  const int row16 = lane & 15, kb = lane >> 4;
  const char* f1b = ws + F1OFF;
  const int nmt = (npix + 47) / 48;

  for (int mt = 0; mt < nmt; ++mt) {
    const int rem = npix - mt * 48;

    half8 av0[8], av1[8], av2[8];
    {
      const int i0 = mt * 48 + row16;
      const int pv0 = (i0 < npix) ? pc[i0] : pc[0];
      const char* a0 = f1b + (size_t)pv0 * 512 + kb * 16;
#pragma unroll
      for (int k = 0; k < 8; ++k) av0[k] = *(const half8*)(a0 + k * 64);
    }
    if (rem > 16) {
      const int i1 = mt * 48 + 16 + row16;
      const int pv1 = (i1 < npix) ? pc[i1] : pc[0];
      const char* a1 = f1b + (size_t)pv1 * 512 + kb * 16;
#pragma unroll
      for (int k = 0; k < 8; ++k) av1[k] = *(const half8*)(a1 + k * 64);
    }
    if (rem > 32) {
      const int i2 = mt * 48 + 32 + row16;
      const int pv2 = (i2 < npix) ? pc[i2] : pc[0];
      const char* a2 = f1b + (size_t)pv2 * 512 + kb * 16;
#pragma unroll
      for (int k = 0; k < 8; ++k) av2[k] = *(const half8*)(a2 + k * 64);
    }

    if (pair == 0) {
      do_level<0>(ws, cent, b, ci, cj, pc, npix, mt, rem, av0, av1, av2, dl, prm, lane);
      do_level<3>(ws, cent, b, ci, cj, pc, npix, mt, rem, av0, av1, av2, dl, prm, lane);
    } else {
      do_level<1>(ws, cent, b, ci, cj, pc, npix, mt, rem, av0, av1, av2, dl, prm, lane);
      do_level<2>(ws, cent, b, ci, cj, pc, npix, mt, rem, av0, av1, av2, dl, prm, lane);
    }
  }
}

// ---------- final transpose: scr[B*HW][328] f16 -> out[B][324][HW] f32 ----------
__global__ __launch_bounds__(256) void k_otrans(const _Float16* __restrict__ scr,
                                                float* __restrict__ out) {
  __shared__ float t[32][33];
  const int b = blockIdx.z;
  const int yx0 = blockIdx.x * 32, c0 = blockIdx.y * 32;
  const int tx = threadIdx.x, ty = threadIdx.y;
#pragma unroll
  for (int i = 0; i < 4; ++i) {
    const int yxi = ty + 8 * i, c = c0 + tx;
    float v = 0.f;
    if (c < 324) {
      const int lv = c / 81, o = c - lv * 81;
      v = (float)scr[((size_t)b * HW_ + yx0 + yxi) * 328 + lv * 82 + o];
    }
    t[yxi][tx] = v;
  }
  __syncthreads();
#pragma unroll
  for (int i = 0; i < 4; ++i) {
    const int c = c0 + ty + 8 * i;
    if (c < 324)
      out[((size_t)b * 324 + c) * HW_ + yx0 + tx] = t[tx][ty + 8 * i];
  }
}

extern "C" void kernel_launch(void* const* d_in, const int* in_sizes, int n_in,
                              void* d_out, int out_size, void* d_ws, size_t ws_size,
                              hipStream_t stream) {
  (void)in_sizes; (void)n_in; (void)out_size; (void)ws_size;
  const float* f1   = (const float*)d_in[0];
  const float* f2   = (const float*)d_in[1];
  const float* cent = (const float*)d_in[2];
  float* out = (float*)d_out;

  char* ws = (char*)d_ws;
  _Float16* f1t = (_Float16*)(ws + F1OFF);
  _Float16* L0  = (_Float16*)(ws + L0OFF);
  _Float16* L1  = (_Float16*)(ws + L1OFF);
  _Float16* L2  = (_Float16*)(ws + L2OFF);
  _Float16* L3  = (_Float16*)(ws + L3OFF);
  int* cnt  = (int*)(ws + CNTOFF);
  int* perm = (int*)(ws + PERMOFF);

  (void)hipMemsetAsync(ws, 0, 4096, stream);   // zero page + cnt

  dim3 tb(32, 8, 1);
  hipLaunchKernelGGL(k_tr2, dim3(HW_ / 32, C_ / 32, 2 * B_), tb, 0, stream,
                     f1, f2, f1t, L0);
  hipLaunchKernelGGL(k_pool3, dim3(B_ * 12 * 12), dim3(256), 0, stream,
                     L0, L1, L2, L3, cent, cnt, perm);

  hipLaunchKernelGGL(k_cell, dim3(1152), dim3(64), 0, stream, ws, cent);

  hipLaunchKernelGGL(k_otrans, dim3(HW_ / 32, 11, B_), tb, 0, stream,
                     (const _Float16*)(ws + SCROFF), out);
}

// Round 18
// 79.118 us; speedup vs baseline: 1.6737x; 1.1267x over previous
//
#include <hip/hip_runtime.h>
#include <stdint.h>

#define B_ 2
#define C_ 256
#define H_ 96
#define W_ 96
#define HW_ (H_*W_)

typedef _Float16 half8 __attribute__((ext_vector_type(8)));
typedef float f32x4 __attribute__((ext_vector_type(4)));

// ---- workspace byte layout ----
#define ZPOFF   0u          // 512 B zero page
#define CNTOFF  512u        // int cnt[576]
#define PERMOFF 4096u       // int perm[576][96]
#define F1OFF   225280u     // f16 (B,HW,C) f1, pre-scaled 1/16
#define L0OFF   9662464u
#define L1OFF   19099648u
#define L2OFF   21458944u
#define L3OFF   22048768u
#define SCROFF  22196224u   // f16 scr[B*HW][328]  (4 levels x 82, dword-aligned)
// end: 34287616

#define CAP 96
#define DLW 226

// ---------- fused transpose: f1 -> f1t (scaled), f2 -> L0 ----------
__global__ __launch_bounds__(256) void k_tr2(const float* __restrict__ f1,
                                             const float* __restrict__ f2,
                                             _Float16* __restrict__ f1t,
                                             _Float16* __restrict__ L0h) {
  __shared__ float t[32][33];
  const int z = blockIdx.z;
  const int b = z & 1;
  const bool is2 = (z >> 1) != 0;
  const float* in = is2 ? f2 : f1;
  _Float16* out = is2 ? L0h : f1t;
  const float scale = is2 ? 1.0f : 0.0625f;

  const int p0 = blockIdx.x * 32, c0 = blockIdx.y * 32;
  const int tx = threadIdx.x, ty = threadIdx.y;
  const float* src = in + ((size_t)b * C_ + c0) * HW_ + p0;
#pragma unroll
  for (int i = 0; i < 4; ++i)
    t[ty + 8 * i][tx] = src[(size_t)(ty + 8 * i) * HW_ + tx];
  __syncthreads();
  _Float16* dst = out + ((size_t)b * HW_ + p0) * C_ + c0;
#pragma unroll
  for (int i = 0; i < 4; ++i)
    dst[(size_t)(ty + 8 * i) * C_ + tx] = (_Float16)(t[tx][ty + 8 * i] * scale);
}

// ---------- fused pools (L1,L2,L3 from L0) + bucket prepass ----------
__global__ __launch_bounds__(256) void k_pool3(const _Float16* __restrict__ L0,
                                               _Float16* __restrict__ L1,
                                               _Float16* __restrict__ L2,
                                               _Float16* __restrict__ L3,
                                               const float* __restrict__ cent,
                                               int* __restrict__ cnt,
                                               int* __restrict__ perm) {
  // fused bucket: first 36864 threads classify one pixel each
  {
    const int t = blockIdx.x * 256 + threadIdx.x;
    if (t < B_ * HW_) {
      const int b = t / HW_, yx = t - b * HW_;
      const float cx = cent[(size_t)b * 2 * HW_ + yx];
      const float cy = cent[(size_t)b * 2 * HW_ + HW_ + yx];
      int ci = (int)(cx * 0.125f); ci = min(max(ci, 0), 11);
      int cj = (int)(cy * 0.25f);  cj = min(max(cj, 0), 23);
      const int cell = b * 288 + cj * 12 + ci;
      const int pos = atomicAdd(&cnt[cell], 1);
      if (pos < CAP) perm[cell * CAP + pos] = t;
    }
  }

  int idx = blockIdx.x;
  const int X = idx % 12; idx /= 12;
  const int Y = idx % 12; const int b = idx / 12;
  const int c = threadIdx.x;

  const _Float16* base = L0 + (((size_t)b * 96 + 8 * Y) * 96 + 8 * X) * C_ + c;
  float s1[4][4];
#pragma unroll
  for (int i = 0; i < 4; ++i)
#pragma unroll
    for (int j = 0; j < 4; ++j) {
      const _Float16* p = base + ((size_t)(2 * i) * 96 + 2 * j) * C_;
      s1[i][j] = ((float)p[0] + (float)p[C_] +
                  (float)p[96 * C_] + (float)p[96 * C_ + C_]) * 0.25f;
    }
#pragma unroll
  for (int i = 0; i < 4; ++i)
#pragma unroll
    for (int j = 0; j < 4; ++j)
      L1[(((size_t)b * 48 + 4 * Y + i) * 48 + 4 * X + j) * C_ + c] = (_Float16)s1[i][j];

  float s2[2][2];
#pragma unroll
  for (int i = 0; i < 2; ++i)
#pragma unroll
    for (int j = 0; j < 2; ++j) {
      s2[i][j] = (s1[2 * i][2 * j] + s1[2 * i][2 * j + 1] +
                  s1[2 * i + 1][2 * j] + s1[2 * i + 1][2 * j + 1]) * 0.25f;
      L2[(((size_t)b * 24 + 2 * Y + i) * 24 + 2 * X + j) * C_ + c] = (_Float16)s2[i][j];
    }

  const float s3 = (s2[0][0] + s2[0][1] + s2[1][0] + s2[1][1]) * 0.25f;
  L3[(((size_t)b * 12 + Y) * 12 + X) * C_ + c] = (_Float16)s3;
}

// ---------- per-(supercell,level) single-wave GEMM + packed epilogue ----------
template <int LVL>
__device__ __forceinline__ void cell_level(char* __restrict__ ws,
                                           const float* __restrict__ cent,
                                           int b, int ci, int cj,
                                           const int* __restrict__ pc, int npix,
                                           _Float16* __restrict__ dl,
                                           float* __restrict__ prm, int lane) {
  constexpr int wl = 96 >> LVL;
  constexpr int Wx = (LVL == 0) ? 17 : (LVL == 1) ? 13 : (LVL == 2) ? 11 : 10;
  constexpr int Hy = (LVL == 0) ? 13 : (LVL == 1) ? 11 : 10;
  constexpr int N = Wx * Hy;
  constexpr int ntiles = (N + 15) >> 4;
  constexpr uint32_t LB = (LVL == 0) ? L0OFF : (LVL == 1) ? L1OFF
                        : (LVL == 2) ? L2OFF : L3OFF;
  constexpr uint32_t PBl = (LVL == 0) ? 4718592u : (LVL == 1) ? 1179648u
                         : (LVL == 2) ? 294912u : 73728u;
  constexpr float inv = 1.0f / (float)(1 << LVL);

  const int FXl = (LVL == 0) ? (ci << 3) : (LVL == 1) ? (ci << 2)
                : (LVL == 2) ? (ci << 1) : ci;
  const int FYl = (LVL == 0) ? (cj << 2) : (LVL == 1) ? (cj << 1)
                : (LVL == 2) ? cj : (cj >> 1);
  const int XW0 = FXl - 4, YW0 = FYl - 4;
  const char* lbase = ws + LB + (size_t)b * PBl;
  const char* zp = ws + ZPOFF;
  const char* f1b = ws + F1OFF;
  char* scrb = ws + SCROFF;

  const int row16 = lane & 15, kb = lane >> 4;
  const int nmt = (npix + 47) / 48;

  for (int mt = 0; mt < nmt; ++mt) {
    const int rem = npix - mt * 48;            // wave-uniform
    const int remc = min(rem, 48);

    half8 av0[8], av1[8], av2[8];
    {
      const int i0 = mt * 48 + row16;
      const int pv0 = (i0 < npix) ? pc[i0] : pc[0];
      const char* a0 = f1b + (size_t)pv0 * 512 + kb * 16;
#pragma unroll
      for (int k = 0; k < 8; ++k) av0[k] = *(const half8*)(a0 + k * 64);
    }
    if (rem > 16) {
      const int i1 = mt * 48 + 16 + row16;
      const int pv1 = (i1 < npix) ? pc[i1] : pc[0];
      const char* a1 = f1b + (size_t)pv1 * 512 + kb * 16;
#pragma unroll
      for (int k = 0; k < 8; ++k) av1[k] = *(const half8*)(a1 + k * 64);
    }
    if (rem > 32) {
      const int i2 = mt * 48 + 32 + row16;
      const int pv2 = (i2 < npix) ? pc[i2] : pc[0];
      const char* a2 = f1b + (size_t)pv2 * 512 + kb * 16;
#pragma unroll
      for (int k = 0; k < 8; ++k) av2[k] = *(const half8*)(a2 + k * 64);
    }

    // epilogue params: one lane per pixel
    if (lane < remc) {
      const int pv = pc[mt * 48 + lane];
      const int yx = pv - b * HW_;
      const float cx = cent[(size_t)b * 2 * HW_ + yx];
      const float cy = cent[(size_t)b * 2 * HW_ + HW_ + yx];
      const float cxl = cx * inv, cyl = cy * inv;
      const float fxl = floorf(cxl), fyl = floorf(cyl);
      const int sxp = (int)fxl - FXl, syp = (int)fyl - FYl;
      prm[lane * 4 + 0] = cxl - fxl;
      prm[lane * 4 + 1] = cyl - fyl;
      ((int*)prm)[lane * 4 + 2] = syp * Wx + sxp;
      ((int*)prm)[lane * 4 + 3] = pv;
    }

#pragma unroll
    for (int j = 0; j < ntiles; ++j) {
      const int n = j * 16 + row16;
      const int sy = n / Wx, sx = n - sy * Wx;
      const int gy = YW0 + sy, gx = XW0 + sx;
      const bool val = (n < N) & (gy >= 0) & (gy < wl) & (gx >= 0) & (gx < wl);
      const char* bp = (val ? (lbase + (((size_t)(gy * wl + gx)) << 9)) : zp)
                       + kb * 16;
      half8 bv[8];
#pragma unroll
      for (int k = 0; k < 8; ++k) bv[k] = *(const half8*)(bp + k * 64);

      f32x4 acc0 = {0.f, 0.f, 0.f, 0.f};
#pragma unroll
      for (int k = 0; k < 8; ++k)
        acc0 = __builtin_amdgcn_mfma_f32_16x16x32_f16(av0[k], bv[k], acc0, 0, 0, 0);
      const int col = j * 16 + row16;
#pragma unroll
      for (int j4 = 0; j4 < 4; ++j4)
        dl[(kb * 4 + j4) * DLW + col] = (_Float16)acc0[j4];

      if (rem > 16) {
        f32x4 acc1 = {0.f, 0.f, 0.f, 0.f};
#pragma unroll
        for (int k = 0; k < 8; ++k)
          acc1 = __builtin_amdgcn_mfma_f32_16x16x32_f16(av1[k], bv[k], acc1, 0, 0, 0);
#pragma unroll
        for (int j4 = 0; j4 < 4; ++j4)
          dl[(kb * 4 + j4 + 16) * DLW + col] = (_Float16)acc1[j4];
      }
      if (rem > 32) {
        f32x4 acc2 = {0.f, 0.f, 0.f, 0.f};
#pragma unroll
        for (int k = 0; k < 8; ++k)
          acc2 = __builtin_amdgcn_mfma_f32_16x16x32_f16(av2[k], bv[k], acc2, 0, 0, 0);
#pragma unroll
        for (int j4 = 0; j4 < 4; ++j4)
          dl[(kb * 4 + j4 + 32) * DLW + col] = (_Float16)acc2[j4];
      }
    }

    // packed epilogue: 2 outputs per lane, one 4-B store
    {
      const int total = remc * 41;
      for (int s = lane; s < total; s += 64) {
        const int p = s / 41;
        const int c = s - p * 41;
        const float wx1 = prm[p * 4 + 0];
        const float wy1 = prm[p * 4 + 1];
        const int n0 = ((const int*)prm)[p * 4 + 2];
        const int pv = ((const int*)prm)[p * 4 + 3];
        const float wx0 = 1.f - wx1, wy0 = 1.f - wy1;
        const _Float16* d = &dl[p * DLW];
        uint32_t packed = 0;
#pragma unroll
        for (int e = 0; e < 2; ++e) {
          const int o = 2 * c + e;
          const int a = o / 9, bq = o - a * 9;
          const int n = n0 + bq * Wx + a;
          const float d00 = (float)d[n],      d10 = (float)d[n + 1];
          const float d01 = (float)d[n + Wx], d11 = (float)d[n + Wx + 1];
          const float v = wy0 * (wx0 * d00 + wx1 * d10) +
                          wy1 * (wx0 * d01 + wx1 * d11);
          const _Float16 h = (_Float16)v;
          packed |= ((uint32_t)*(const uint16_t*)&h) << (16 * e);
        }
        *(uint32_t*)(scrb + (size_t)pv * 656 + LVL * 164 + c * 4) = packed;
      }
    }
  }
}

// static XCD-banded single-level tasks (R13 best structure)
__global__ __launch_bounds__(64, 2) void k_cell(char* __restrict__ ws,
                                                const float* __restrict__ cent) {
  __shared__ _Float16 dl[48 * DLW];   // 21.2 KB
  __shared__ float prm[48 * 4];

  const int bx = blockIdx.x;                 // 0..2303
  const int xcd = bx & 7, slot = bx >> 3;    // slot 0..287
  const int b = xcd >> 2, band = xcd & 3;
  const int lvl = slot / 72;
  const int rem = slot - lvl * 72;
  const int cjb = rem / 12, ci = rem - cjb * 12;
  const int cj = band * 6 + cjb;
  const int cell = b * 288 + cj * 12 + ci;

  const int* cnt = (const int*)(ws + CNTOFF);
  const int npix = min(cnt[cell], CAP);
  if (npix == 0) return;
  const int* pc = (const int*)(ws + PERMOFF) + cell * CAP;

  const int lane = threadIdx.x;
  switch (lvl) {
    case 0: cell_level<0>(ws, cent, b, ci, cj, pc, npix, dl, prm, lane); break;
    case 1: cell_level<1>(ws, cent, b, ci, cj, pc, npix, dl, prm, lane); break;
    case 2: cell_level<2>(ws, cent, b, ci, cj, pc, npix, dl, prm, lane); break;
    default: cell_level<3>(ws, cent, b, ci, cj, pc, npix, dl, prm, lane); break;
  }
}

// ---------- final transpose: scr[B*HW][328] f16 -> out[B][324][HW] f32 ----------
__global__ __launch_bounds__(256) void k_otrans(const _Float16* __restrict__ scr,
                                                float* __restrict__ out) {
  __shared__ float t[32][33];
  const int b = blockIdx.z;
  const int yx0 = blockIdx.x * 32, c0 = blockIdx.y * 32;
  const int tx = threadIdx.x, ty = threadIdx.y;
#pragma unroll
  for (int i = 0; i < 4; ++i) {
    const int yxi = ty + 8 * i, c = c0 + tx;
    float v = 0.f;
    if (c < 324) {
      const int lv = c / 81, o = c - lv * 81;
      v = (float)scr[((size_t)b * HW_ + yx0 + yxi) * 328 + lv * 82 + o];
    }
    t[yxi][tx] = v;
  }
  __syncthreads();
#pragma unroll
  for (int i = 0; i < 4; ++i) {
    const int c = c0 + ty + 8 * i;
    if (c < 324)
      out[((size_t)b * 324 + c) * HW_ + yx0 + tx] = t[tx][ty + 8 * i];
  }
}

extern "C" void kernel_launch(void* const* d_in, const int* in_sizes, int n_in,
                              void* d_out, int out_size, void* d_ws, size_t ws_size,
                              hipStream_t stream) {
  (void)in_sizes; (void)n_in; (void)out_size; (void)ws_size;
  const float* f1   = (const float*)d_in[0];
  const float* f2   = (const float*)d_in[1];
  const float* cent = (const float*)d_in[2];
  float* out = (float*)d_out;

  char* ws = (char*)d_ws;
  _Float16* f1t = (_Float16*)(ws + F1OFF);
  _Float16* L0  = (_Float16*)(ws + L0OFF);
  _Float16* L1  = (_Float16*)(ws + L1OFF);
  _Float16* L2  = (_Float16*)(ws + L2OFF);
  _Float16* L3  = (_Float16*)(ws + L3OFF);
  int* cnt  = (int*)(ws + CNTOFF);
  int* perm = (int*)(ws + PERMOFF);

  (void)hipMemsetAsync(ws, 0, 4096, stream);   // zero page + cnt

  dim3 tb(32, 8, 1);
  hipLaunchKernelGGL(k_tr2, dim3(HW_ / 32, C_ / 32, 2 * B_), tb, 0, stream,
                     f1, f2, f1t, L0);
  hipLaunchKernelGGL(k_pool3, dim3(B_ * 12 * 12), dim3(256), 0, stream,
                     L0, L1, L2, L3, cent, cnt, perm);

  hipLaunchKernelGGL(k_cell, dim3(2304), dim3(64), 0, stream, ws, cent);

  hipLaunchKernelGGL(k_otrans, dim3(HW_ / 32, 11, B_), tb, 0, stream,
                     (const _Float16*)(ws + SCROFF), out);
}